// Round 1
// 906.044 us; speedup vs baseline: 1.0194x; 1.0194x over previous
//
#include <hip/hip_runtime.h>

// HybridEulerIntegrator R3: 16 lanes/element, 4 hidden units/lane,
// 4-way rcp amortization (one v_rcp_f32 per 4 sigmoid terms), and
// NEW: pure-DPP 16-lane butterfly reduction (v_add_f32_dpp) replacing
// the ds_bpermute-based __shfl_xor chain. Patterns chosen so the sum is
// BIT-IDENTICAL to the xor1/2/4/8 butterfly:
//   xor1 -> quad_perm[1,0,3,2] (0xB1)
//   xor2 -> quad_perm[2,3,0,1] (0x4E)
//   xor4 -> row_half_mirror (0x141 = xor7; equals xor4 on the stage-2
//           partial sums, which are invariant under xor{1,2,3})
//   xor8 -> row_ror:8 (0x128, exact xor8)
// This removes 4 serial ds_bpermute + s_waitcnt lgkmcnt(0) per step
// (~120+ cycles of LDS-pipe latency in the serial a_t -> a_{t+1} chain).
// 16384 elem * 16 lanes = 262144 threads = 4096 waves = 4 waves/SIMD.

#define SEQ_T  2048
#define NB     16384
#define NH     64
#define C_GAIN 0.001f
#define K2LOG2E 2.8853900817779268f   // 2/ln(2)
#define QCLAMP  30.0f                 // e = 2^q <= 2^30; 4-product <= 2^120

struct LaneW {
    float w1x[4], w1a[4], b1v[4], w2v[4];
    float b2pp;   // b2 + sum_j w2_j  (full 64-unit sum)
};

// one butterfly stage: R += R_from_dpp_pattern(ctrl)
#define DPP_ADD(R, ctrl)                                                   \
    (R) += __int_as_float(__builtin_amdgcn_update_dpp(                     \
        0, __float_as_int(R), (ctrl), 0xF, 0xF, true))

__device__ __forceinline__ float allreduce16_dpp(float R) {
    DPP_ADD(R, 0x0B1);  // quad_perm [1,0,3,2]  == xor1
    DPP_ADD(R, 0x04E);  // quad_perm [2,3,0,1]  == xor2
    DPP_ADD(R, 0x141);  // row_half_mirror (xor7 == xor4 at this stage)
    DPP_ADD(R, 0x128);  // row_ror:8            == xor8
    return R;
}

__device__ __forceinline__ float do_step(float a, float xv, const LaneW& W) {
    float q0 = fmaf(xv, W.w1x[0], fmaf(a, W.w1a[0], W.b1v[0]));
    float q1 = fmaf(xv, W.w1x[1], fmaf(a, W.w1a[1], W.b1v[1]));
    float q2 = fmaf(xv, W.w1x[2], fmaf(a, W.w1a[2], W.b1v[2]));
    float q3 = fmaf(xv, W.w1x[3], fmaf(a, W.w1a[3], W.b1v[3]));
    q0 = fminf(q0, QCLAMP); q1 = fminf(q1, QCLAMP);
    q2 = fminf(q2, QCLAMP); q3 = fminf(q3, QCLAMP);
    float f0 = __builtin_amdgcn_exp2f(q0) + 1.0f;
    float f1 = __builtin_amdgcn_exp2f(q1) + 1.0f;
    float f2 = __builtin_amdgcn_exp2f(q2) + 1.0f;
    float f3 = __builtin_amdgcn_exp2f(q3) + 1.0f;
    float g01 = f0 * f1, g23 = f2 * f3;
    float n01 = W.w2v[0] * f1; n01 = fmaf(W.w2v[1], f0, n01);
    float n23 = W.w2v[2] * f3; n23 = fmaf(W.w2v[3], f2, n23);
    float D = g01 * g23;
    float N = n01 * g23;  N = fmaf(n23, g01, N);
    float R = N * __builtin_amdgcn_rcpf(D);   // = sum_j w2_j / (1 + e^{2p_j})

    // pure-VALU butterfly over the 16 hidden-chunk lanes (no LDS pipe)
    R = allreduce16_dpp(R);
    float dk = fmaf(-2.0f, R, W.b2pp);
    return fmaf(dk * dk * C_GAIN, dk, a);   // a + C*dk^3
}

__global__ __launch_bounds__(256, 4) void integ_kernel(
        const float* __restrict__ x,  const float* __restrict__ a0,
        const float* __restrict__ W1, const float* __restrict__ b1,
        const float* __restrict__ W2, const float* __restrict__ b2,
        float* __restrict__ out) {
    const int lane = threadIdx.x & 63;
    const int wv   = threadIdx.x >> 6;     // wave in block (0..3)
    const int e    = lane >> 4;            // element slot   (0..3)
    const int h    = lane & 15;            // hidden chunk   (0..15)
    const int b    = blockIdx.x * 16 + wv * 4 + e;
    const int j0   = h * 4;

    LaneW W;
    float sw2 = 0.0f;
#pragma unroll
    for (int u = 0; u < 4; ++u) {
        W.w1x[u] = W1[j0 + u] * K2LOG2E;        // W1 row 0: weight on x
        W.w1a[u] = W1[NH + j0 + u] * K2LOG2E;   // W1 row 1: weight on a
        W.b1v[u] = b1[j0 + u] * K2LOG2E;
        W.w2v[u] = W2[j0 + u];
        sw2 += W.w2v[u];
    }
    sw2 = allreduce16_dpp(sw2);   // bit-identical to the xor butterfly
    W.b2pp = b2[0] + sw2;

    float a = a0[b];
    const float* xp = x + b;

    // software prefetch, distance 4, two register banks of 4 steps each
    float xA[4], xB[4];
#pragma unroll
    for (int i = 0; i < 4; ++i) xA[i] = xp[i * NB];

    for (int t8 = 0; t8 < SEQ_T; t8 += 8) {
        // prefetch bank B (steps t8+4 .. t8+7)
#pragma unroll
        for (int i = 0; i < 4; ++i) xB[i] = xp[(t8 + 4 + i) * NB];

#pragma unroll
        for (int k = 0; k < 4; ++k) {
            a = do_step(a, xA[k], W);
            if (h == 0) out[(t8 + k) * NB + b] = a;
        }

        // prefetch bank A (steps t8+8 .. t8+11), skip on last iteration
        if (t8 + 8 < SEQ_T) {
#pragma unroll
            for (int i = 0; i < 4; ++i) xA[i] = xp[(t8 + 8 + i) * NB];
        }

#pragma unroll
        for (int k = 0; k < 4; ++k) {
            a = do_step(a, xB[k], W);
            if (h == 0) out[(t8 + 4 + k) * NB + b] = a;
        }
    }
}

extern "C" void kernel_launch(void* const* d_in, const int* in_sizes, int n_in,
                              void* d_out, int out_size, void* d_ws, size_t ws_size,
                              hipStream_t stream) {
    const float* x  = (const float*)d_in[0];
    const float* a0 = (const float*)d_in[1];
    const float* W1 = (const float*)d_in[2];
    const float* b1 = (const float*)d_in[3];
    const float* W2 = (const float*)d_in[4];
    const float* b2 = (const float*)d_in[5];
    float* out = (float*)d_out;

    dim3 grid(NB / 16);
    dim3 block(256);
    hipLaunchKernelGGL(integ_kernel, grid, block, 0, stream,
                       x, a0, W1, b1, W2, b2, out);
}